// Round 14
// baseline (1096.406 us; speedup 1.0000x reference)
//
#include <hip/hip_runtime.h>
#include <cstdint>
#include <cstddef>

typedef short bf16x8 __attribute__((ext_vector_type(8)));
typedef float f32x4 __attribute__((ext_vector_type(4)));
typedef unsigned short us4 __attribute__((ext_vector_type(4)));

#define DEV static __device__ __forceinline__

DEV unsigned short f2bf(float f) {
  union { float f; unsigned u; } v; v.f = f;
  unsigned r = v.u + 0x7FFFu + ((v.u >> 16) & 1u);
  return (unsigned short)(r >> 16);
}

DEV void gll16(const void* g, void* l) {
  __builtin_amdgcn_global_load_lds((const __attribute__((address_space(1))) void*)g,
                                   (__attribute__((address_space(3))) void*)l,
                                   16, 0, 0);
}

// ---------------------------------------------------------------------------
// Device bodies (shared by fused wrappers)
// ---------------------------------------------------------------------------
DEV void embed_body(const int* __restrict__ x, const float* __restrict__ te,
                    const float* __restrict__ pe, float* __restrict__ hf,
                    unsigned short* __restrict__ hb, int row, int tid) {
  int t = row & 1023;
  int tok = x[row];
  float4 v = ((const float4*)(te + (size_t)tok * 1024))[tid];
  float4 p = ((const float4*)(pe + (size_t)t * 1024))[tid];
  v.x += p.x; v.y += p.y; v.z += p.z; v.w += p.w;
  ((float4*)(hf + (size_t)row * 1024))[tid] = v;
  us4 bv; bv[0] = f2bf(v.x); bv[1] = f2bf(v.y); bv[2] = f2bf(v.z); bv[3] = f2bf(v.w);
  ((us4*)(hb + (size_t)row * 1024))[tid] = bv;
}

DEV void wconv_body(const float* __restrict__ W, unsigned short* __restrict__ Wt,
                    int K, int N, int b, float (*tile)[33], int tid) {
  const int nb = N >> 5;
  const int n0 = (b % nb) * 32, k0 = (b / nb) * 32;
  const int tx = tid & 31, ty = tid >> 5;
#pragma unroll
  for (int i = 0; i < 4; ++i)
    tile[ty * 4 + i][tx] = W[(size_t)(k0 + ty * 4 + i) * N + n0 + tx];
  __syncthreads();
#pragma unroll
  for (int i = 0; i < 4; ++i)
    Wt[(size_t)(n0 + ty * 4 + i) * K + k0 + tx] = f2bf(tile[tx][ty * 4 + i]);
}

template <int NP>
DEV void ln_body(const float* __restrict__ a1, const float* __restrict__ res,
                 const float* __restrict__ s, const float* __restrict__ bb,
                 float* __restrict__ out_f, unsigned short* __restrict__ out_b,
                 int row, int tid, float* red) {
  float4 x = ((const float4*)(a1 + (size_t)row * 1024))[tid];
  float4 rv = ((const float4*)(res + (size_t)row * 1024))[tid];
  x.x += rv.x; x.y += rv.y; x.z += rv.z; x.w += rv.w;
#pragma unroll
  for (int pimg = 1; pimg < NP; ++pimg) {
    float4 x2 = ((const float4*)(a1 + (size_t)pimg * 2097152 + (size_t)row * 1024))[tid];
    x.x += x2.x; x.y += x2.y; x.z += x2.z; x.w += x2.w;
  }
  float sum = x.x + x.y + x.z + x.w;
  float sq = x.x * x.x + x.y * x.y + x.z * x.z + x.w * x.w;
#pragma unroll
  for (int mm = 1; mm < 64; mm <<= 1) {
    sum += __shfl_xor(sum, mm, 64);
    sq += __shfl_xor(sq, mm, 64);
  }
  int wid = tid >> 6, lane = tid & 63;
  if (lane == 0) { red[wid] = sum; red[4 + wid] = sq; }
  __syncthreads();
  sum = red[0] + red[1] + red[2] + red[3];
  sq = red[4] + red[5] + red[6] + red[7];
  float mean = sum * (1.f / 1024.f);
  float var = sq * (1.f / 1024.f) - mean * mean;
  float rstd = rsqrtf(var + 1e-5f);
  float4 sv = ((const float4*)s)[tid];
  float4 bv = ((const float4*)bb)[tid];
  float4 y;
  y.x = (x.x - mean) * rstd * sv.x + bv.x;
  y.y = (x.y - mean) * rstd * sv.y + bv.y;
  y.z = (x.z - mean) * rstd * sv.z + bv.z;
  y.w = (x.w - mean) * rstd * sv.w + bv.w;
  ((float4*)(out_f + (size_t)row * 1024))[tid] = y;
  us4 ob; ob[0] = f2bf(y.x); ob[1] = f2bf(y.y); ob[2] = f2bf(y.z); ob[3] = f2bf(y.w);
  ((us4*)(out_b + (size_t)row * 1024))[tid] = ob;
}

DEV void wconv5_select(int bid, const float* Wqf, const float* Wkf,
                       const float* Wvf, const float* W1f, const float* W2f,
                       unsigned short* wsc, float (*tile)[33], int tid) {
  const float* W; unsigned short* Wt; int K, N, b;
  if (bid < 3072) {
    const int sgl = bid >> 10; b = bid & 1023;
    W = sgl == 0 ? Wqf : (sgl == 1 ? Wkf : Wvf);
    Wt = wsc + (size_t)sgl * 1048576; K = 1024; N = 1024;
  } else if (bid < 7168) {
    b = bid - 3072; W = W1f; Wt = wsc + 3145728; K = 1024; N = 4096;
  } else {
    b = bid - 7168; W = W2f; Wt = wsc + 7340032; K = 4096; N = 1024;
  }
  wconv_body(W, Wt, K, N, b, tile, tid);
}

// ---------------------------------------------------------------------------
// Fused wrappers
// ---------------------------------------------------------------------------
__global__ __launch_bounds__(256) void embed_wconv_kernel(
    const int* __restrict__ x, const float* __restrict__ te,
    const float* __restrict__ pe, float* __restrict__ hf,
    unsigned short* __restrict__ hb,
    const float* __restrict__ Wqf, const float* __restrict__ Wkf,
    const float* __restrict__ Wvf, const float* __restrict__ W1f,
    const float* __restrict__ W2f, unsigned short* __restrict__ wsc) {
  __shared__ float tile[32][33];
  const int bid = blockIdx.x;
  if (bid < 2048) {
    embed_body(x, te, pe, hf, hb, bid, threadIdx.x);
    return;
  }
  wconv5_select(bid - 2048, Wqf, Wkf, Wvf, W1f, W2f, wsc, tile, threadIdx.x);
}

template <int NP>
__global__ __launch_bounds__(256) void ln_wconv5_kernel(
    const float* __restrict__ a1, const float* __restrict__ res,
    const float* __restrict__ s, const float* __restrict__ bb,
    float* __restrict__ out_f, unsigned short* __restrict__ out_b,
    const float* __restrict__ Wqf, const float* __restrict__ Wkf,
    const float* __restrict__ Wvf, const float* __restrict__ W1f,
    const float* __restrict__ W2f, unsigned short* __restrict__ wsc) {
  __shared__ float tile[32][33];
  __shared__ float red[8];
  const int bid = blockIdx.x;
  if (bid < 2048) {
    ln_body<NP>(a1, res, s, bb, out_f, out_b, bid, threadIdx.x, red);
    return;
  }
  wconv5_select(bid - 2048, Wqf, Wkf, Wvf, W1f, W2f, wsc, tile, threadIdx.x);
}

template <int NP>
__global__ __launch_bounds__(256) void ln_add_kernel(
    const float* __restrict__ a1, const float* __restrict__ res,
    const float* __restrict__ s, const float* __restrict__ bb,
    float* __restrict__ out_f, unsigned short* __restrict__ out_b) {
  __shared__ float red[8];
  ln_body<NP>(a1, res, s, bb, out_f, out_b, blockIdx.x, threadIdx.x, red);
}

__global__ __launch_bounds__(256) void wconv_kernel(
    const float* __restrict__ W, unsigned short* __restrict__ Wt, int K, int N) {
  __shared__ float tile[32][33];
  const int nb = N >> 5;
  wconv_body(W, Wt, K, N, blockIdx.y * nb + blockIdx.x, tile, threadIdx.x);
}

// ---------------------------------------------------------------------------
// gemm5: 2-phase GEMM (single-buffer, 2 barriers), BM x 128, 8 waves.
// ---------------------------------------------------------------------------
template <int BM, int EPI>
__global__ __launch_bounds__(512) void gemm5_kernel(
    const unsigned short* __restrict__ A, const unsigned short* __restrict__ Bt,
    const float* __restrict__ bias1, const float* __restrict__ bias2,
    const float* __restrict__ bias3, void* __restrict__ C1,
    void* __restrict__ C2, void* __restrict__ C3,
    int M, int N, int Kstride, int klen, int nbm) {
  constexpr int BN = 128, BK = 64;
  constexpr int MFR = BM / 64;
  constexpr int AIT = BM / 64;
  __shared__ unsigned short lA[BM * BK];
  __shared__ unsigned short lB[BN * BK];
  const int tid = threadIdx.x;
  const int wid = tid >> 6, lane = tid & 63;
  const int g = lane >> 4, c = lane & 15;
  const int wm = wid >> 1, wn = wid & 1;

  const int nwg = gridDim.x;
  const int q = nwg >> 3, r = nwg & 7;
  const int xcd = blockIdx.x & 7, jj = blockIdx.x >> 3;
  const int wgid = (xcd < r) ? (xcd * (q + 1) + jj)
                             : (r * (q + 1) + (xcd - r) * q + jj);
  const int bm = (wgid % nbm) * BM;
  const int bn = (wgid / nbm) * BN;
  const int k0 = blockIdx.z * klen;

  f32x4 acc[MFR][4];
#pragma unroll
  for (int mi = 0; mi < MFR; ++mi)
#pragma unroll
    for (int ni = 0; ni < 4; ++ni) acc[mi][ni] = f32x4{0.f, 0.f, 0.f, 0.f};

  for (int kb = 0; kb < klen; kb += BK) {
#pragma unroll
    for (int it = 0; it < AIT; ++it) {
      int chunk = it * 512 + tid;
      int row = chunk >> 3, cr = chunk & 7;
      int sc = cr ^ (row & 7);
      gll16(A + (size_t)(bm + row) * Kstride + k0 + kb + sc * 8,
            lA + (size_t)(it * 512 + wid * 64) * 8);
    }
#pragma unroll
    for (int it = 0; it < 2; ++it) {
      int chunk = it * 512 + tid;
      int row = chunk >> 3, cr = chunk & 7;
      int sc = cr ^ (row & 7);
      gll16(Bt + (size_t)(bn + row) * Kstride + k0 + kb + sc * 8,
            lB + (size_t)(it * 512 + wid * 64) * 8);
    }
    __syncthreads();
#pragma unroll
    for (int kk = 0; kk < 2; ++kk) {
      bf16x8 af[MFR], bfr[4];
#pragma unroll
      for (int mi = 0; mi < MFR; ++mi) {
        int row = wm * (BM / 4) + mi * 16 + c;
        int ch = (kk * 4 + g) ^ (row & 7);
        af[mi] = *(const bf16x8*)(lA + row * BK + ch * 8);
      }
#pragma unroll
      for (int ni = 0; ni < 4; ++ni) {
        int row = wn * 64 + ni * 16 + c;
        int ch = (kk * 4 + g) ^ (row & 7);
        bfr[ni] = *(const bf16x8*)(lB + row * BK + ch * 8);
      }
#pragma unroll
      for (int mi = 0; mi < MFR; ++mi)
#pragma unroll
        for (int ni = 0; ni < 4; ++ni)
          acc[mi][ni] = __builtin_amdgcn_mfma_f32_16x16x32_bf16(
              af[mi], bfr[ni], acc[mi][ni], 0, 0, 0);
    }
    __syncthreads();
  }

  const bool z0 = (blockIdx.z == 0);
#pragma unroll
  for (int mi = 0; mi < MFR; ++mi) {
    const int row0 = bm + wm * (BM / 4) + mi * 16 + g * 4;
#pragma unroll
    for (int ni = 0; ni < 4; ++ni) {
      const int col = bn + wn * 64 + ni * 16 + c;
      if constexpr (EPI == 0) {
        float* C = (float*)C1 + (size_t)blockIdx.z * M * N;
        const float bv = z0 ? bias1[col] : 0.f;
#pragma unroll
        for (int rr = 0; rr < 4; ++rr)
          C[(size_t)(row0 + rr) * N + col] = acc[mi][ni][rr] + bv;
      } else if constexpr (EPI == 2) {
        const float bv = bias1[col];
#pragma unroll
        for (int rr = 0; rr < 4; ++rr)
          ((unsigned short*)C1)[(size_t)(row0 + rr) * N + col] =
              f2bf(fmaxf(acc[mi][ni][rr] + bv, 0.f));
      } else {  // EPI == 4: QKV scatter
        if (col < 1024) {
          const float bv = bias1[col];
#pragma unroll
          for (int rr = 0; rr < 4; ++rr)
            ((unsigned short*)C1)[(size_t)(row0 + rr) * 1024 + col] =
                f2bf(acc[mi][ni][rr] + bv);
        } else if (col < 2048) {
          const float bv = bias2[col - 1024];
#pragma unroll
          for (int rr = 0; rr < 4; ++rr)
            ((unsigned short*)C2)[(size_t)(row0 + rr) * 1024 + (col - 1024)] =
                f2bf(acc[mi][ni][rr] + bv);
        } else {
          const int cp = col - 2048;
          const float bv = bias3[cp];
          const int hh = cp >> 6, hd = cp & 63;
#pragma unroll
          for (int rr = 0; rr < 4; ++rr) {
            const int row = row0 + rr;
            const int b = row >> 10, t = row & 1023;
            ((unsigned short*)C3)[(size_t)((b * 16 + hh) * 64 + hd) * 1024 + t] =
                f2bf(acc[mi][ni][rr] + bv);
          }
        }
      }
    }
  }
}

// ---------------------------------------------------------------------------
// Flash attention, QBLK=128, KVBLK=128: 512 threads = 8 waves x 16 q-rows.
// ---------------------------------------------------------------------------
__global__ __launch_bounds__(512) void attn_kernel(
    const unsigned short* __restrict__ q, const unsigned short* __restrict__ k,
    const unsigned short* __restrict__ vt, float* __restrict__ o) {
  __shared__ unsigned short lK[128 * 64];      // 16 KB
  __shared__ unsigned short lV[64 * 128];      // 16 KB
  __shared__ unsigned short lP[8][16 * 128];   // 32 KB
  const int tid = threadIdx.x, wid = tid >> 6, lane = tid & 63;
  const int g = lane >> 4, c = lane & 15;
  const int qb = blockIdx.x * 128;
  const int h = blockIdx.y;
  const int b = blockIdx.z;
  const int qw = qb + wid * 16;

  bf16x8 aq[2];
#pragma unroll
  for (int kk = 0; kk < 2; ++kk)
    aq[kk] = *(const bf16x8*)(q + (size_t)(b * 1024 + qw + c) * 1024 + h * 64 + kk * 32 + g * 8);

  float m_run[4], l_run[4];
  f32x4 acc_o[4];
#pragma unroll
  for (int rr = 0; rr < 4; ++rr) { m_run[rr] = -INFINITY; l_run[rr] = 0.f; }
#pragma unroll
  for (int ni = 0; ni < 4; ++ni) acc_o[ni] = f32x4{0.f, 0.f, 0.f, 0.f};

  const int ntiles = blockIdx.x + 1;
  for (int kt = 0; kt < ntiles; ++kt) {
#pragma unroll
    for (int it = 0; it < 2; ++it) {
      int chunk = it * 512 + tid;
      int row = chunk >> 3, cr = chunk & 7;
      int sc = cr ^ (row & 7);
      gll16(k + (size_t)(b * 1024 + kt * 128 + row) * 1024 + h * 64 + sc * 8,
            lK + (size_t)(it * 512 + wid * 64) * 8);
    }
#pragma unroll
    for (int it = 0; it < 2; ++it) {
      int chunk = it * 512 + tid;
      int row = chunk >> 4, cr = chunk & 15;
      int sc = cr ^ (row & 7);
      gll16(vt + (size_t)((b * 16 + h) * 64 + row) * 1024 + kt * 128 + sc * 8,
            lV + (size_t)(it * 512 + wid * 64) * 8);
    }
    __syncthreads();

    f32x4 accs[8];
#pragma unroll
    for (int ni = 0; ni < 8; ++ni) accs[ni] = f32x4{0.f, 0.f, 0.f, 0.f};
    __builtin_amdgcn_s_setprio(1);
#pragma unroll
    for (int kk = 0; kk < 2; ++kk)
#pragma unroll
      for (int ni = 0; ni < 8; ++ni) {
        int row = ni * 16 + c;
        int ch = (kk * 4 + g) ^ (row & 7);
        bf16x8 kf = *(const bf16x8*)(lK + row * 64 + ch * 8);
        accs[ni] = __builtin_amdgcn_mfma_f32_16x16x32_bf16(aq[kk], kf, accs[ni], 0, 0, 0);
      }
    __builtin_amdgcn_s_setprio(0);

    const bool diag = (kt == ntiles - 1);
    float p[8][4], rowmax[4];
#pragma unroll
    for (int rr = 0; rr < 4; ++rr) rowmax[rr] = -INFINITY;
#pragma unroll
    for (int ni = 0; ni < 8; ++ni)
#pragma unroll
      for (int rr = 0; rr < 4; ++rr) {
        float s = accs[ni][rr] * 0.125f;
        if (diag) {
          int ktok = kt * 128 + ni * 16 + c;
          int qtok = qw + g * 4 + rr;
          if (ktok > qtok) s = -INFINITY;
        }
        p[ni][rr] = s;
        rowmax[rr] = fmaxf(rowmax[rr], s);
      }
#pragma unroll
    for (int mm = 1; mm < 16; mm <<= 1)
#pragma unroll
      for (int rr = 0; rr < 4; ++rr)
        rowmax[rr] = fmaxf(rowmax[rr], __shfl_xor(rowmax[rr], mm, 64));

    float alpha[4];
#pragma unroll
    for (int rr = 0; rr < 4; ++rr) {
      float mn = fmaxf(m_run[rr], rowmax[rr]);
      alpha[rr] = __expf(m_run[rr] - mn);
      m_run[rr] = mn;
    }
#pragma unroll
    for (int ni = 0; ni < 8; ++ni)
#pragma unroll
      for (int rr = 0; rr < 4; ++rr) p[ni][rr] = __expf(p[ni][rr] - m_run[rr]);

    float rowsum[4];
#pragma unroll
    for (int rr = 0; rr < 4; ++rr)
      rowsum[rr] = ((p[0][rr] + p[1][rr]) + (p[2][rr] + p[3][rr])) +
                   ((p[4][rr] + p[5][rr]) + (p[6][rr] + p[7][rr]));
#pragma unroll
    for (int mm = 1; mm < 16; mm <<= 1)
#pragma unroll
      for (int rr = 0; rr < 4; ++rr) rowsum[rr] += __shfl_xor(rowsum[rr], mm, 64);
#pragma unroll
    for (int rr = 0; rr < 4; ++rr) l_run[rr] = l_run[rr] * alpha[rr] + rowsum[rr];
#pragma unroll
    for (int ni = 0; ni < 4; ++ni)
#pragma unroll
      for (int rr = 0; rr < 4; ++rr) acc_o[ni][rr] *= alpha[rr];

#pragma unroll
    for (int ni = 0; ni < 8; ++ni)
#pragma unroll
      for (int rr = 0; rr < 4; ++rr) {
        int qrow = g * 4 + rr;
        int tok = ni * 16 + c;
        int ch = (tok >> 3) ^ (qrow & 7);
        lP[wid][qrow * 128 + ch * 8 + (tok & 7)] = f2bf(p[ni][rr]);
      }

    __builtin_amdgcn_s_setprio(1);
#pragma unroll
    for (int kk = 0; kk < 4; ++kk) {
      int kc = kk * 4 + g;
      int chp = kc ^ (c & 7);
      bf16x8 pa = *(const bf16x8*)(&lP[wid][c * 128 + chp * 8]);
#pragma unroll
      for (int ni = 0; ni < 4; ++ni) {
        int row = ni * 16 + c;
        int ch = kc ^ (row & 7);
        bf16x8 vf = *(const bf16x8*)(lV + row * 128 + ch * 8);
        acc_o[ni] = __builtin_amdgcn_mfma_f32_16x16x32_bf16(pa, vf, acc_o[ni], 0, 0, 0);
      }
    }
    __builtin_amdgcn_s_setprio(0);
    __syncthreads();
  }

#pragma unroll
  for (int ni = 0; ni < 4; ++ni)
#pragma unroll
    for (int rr = 0; rr < 4; ++rr) {
      int row = b * 1024 + qw + g * 4 + rr;
      int col = h * 64 + ni * 16 + c;
      o[(size_t)row * 1024 + col] = acc_o[ni][rr] / l_run[rr];
    }
}

// ---------------------------------------------------------------------------
extern "C" void kernel_launch(void* const* d_in, const int* in_sizes, int n_in,
                              void* d_out, int out_size, void* d_ws, size_t ws_size,
                              hipStream_t stream) {
  const int D = 1024, DFF = 4096, V = 32000, L = 6;
  const int* x = (const int*)d_in[0];
  const float* tok_emb = (const float*)d_in[1];
  const float* pos_emb = (const float*)d_in[2];
  const float* Wq = (const float*)d_in[3];  const float* bq = (const float*)d_in[4];
  const float* Wk = (const float*)d_in[5];  const float* bk = (const float*)d_in[6];
  const float* Wv = (const float*)d_in[7];  const float* bv = (const float*)d_in[8];
  const float* ln1s = (const float*)d_in[9];  const float* ln1b = (const float*)d_in[10];
  const float* W1 = (const float*)d_in[11];  const float* b1 = (const float*)d_in[12];
  const float* W2 = (const float*)d_in[13];  const float* b2 = (const float*)d_in[14];
  const float* ln2s = (const float*)d_in[15]; const float* ln2b = (const float*)d_in[16];
  const float* Wout = (const float*)d_in[17]; const float* bout = (const float*)d_in[18];

  char* ws = (char*)d_ws;
  float* h_res = (float*)(ws + 0);                     //  8 MB [2048][1024] f32
  float* hi_res = (float*)(ws + 8388608);              //  8 MB
  float* tmp = (float*)(ws + 16777216);                //  8 MB (attn out)
  unsigned short* hbf = (unsigned short*)(ws + 25165824);   // 4 MB
  unsigned short* qb_ = (unsigned short*)(ws + 29360128);   // 4 MB
  unsigned short* kb_ = (unsigned short*)(ws + 33554432);   // 4 MB
  unsigned short* vtb = (unsigned short*)(ws + 37748736);   // 4 MB V^T
  unsigned short* ffn1 = (unsigned short*)(ws + 41943040);  // 16 MB [2048][4096]
  unsigned short* wsc = (unsigned short*)(ws + 58720256);   // weights (64MB for logits)
  float* part = (float*)(ws + 58720256 + 25165824);    // 32 MB FFN2 partials
  // (part aliases the logits-weight zone; wconv_out runs after last part use)

  // embed + wconv5(layer 0) fused
  embed_wconv_kernel<<<13312, 256, 0, stream>>>(
      x, tok_emb, pos_emb, h_res, hbf,
      Wq, Wk, Wv, W1, W2, wsc);

  for (int l = 0; l < L; ++l) {
    // QKV fused GEMM (N=3072): BM=128, grid 16x24=384 blocks
    gemm5_kernel<128, 4><<<384, 512, 0, stream>>>(
        hbf, wsc, bq + l * D, bk + l * D, bv + l * D, qb_, kb_, vtb,
        2048, 3072, D, D, 16);
    // attention (QBLK=128) -> tmp
    attn_kernel<<<dim3(8, 16, 2), 512, 0, stream>>>(qb_, kb_, vtb, tmp);
    // hi = LN1(attn + h)
    ln_add_kernel<1><<<2048, 256, 0, stream>>>(
        tmp, h_res, ln1s + l * D, ln1b + l * D, hi_res, hbf);
    // FFN1 (relu, bf16 out): proven gemm5, grid 8x32=256
    gemm5_kernel<256, 2><<<256, 512, 0, stream>>>(
        hbf, wsc + 3145728, b1 + l * DFF, nullptr, nullptr, ffn1, nullptr, nullptr,
        2048, DFF, D, D, 8);
    // FFN2 split-K=4 -> part[0..3]
    gemm5_kernel<256, 0><<<dim3(64, 1, 4), 512, 0, stream>>>(
        ffn1, wsc + 7340032, b2 + l * D, nullptr, nullptr, part, nullptr, nullptr,
        2048, D, DFF, 1024, 8);
    // h = LN2(part0..3 + hi), fused with wconv5 of NEXT layer
    if (l < L - 1) {
      ln_wconv5_kernel<4><<<13312, 256, 0, stream>>>(
          part, hi_res, ln2s + l * D, ln2b + l * D, h_res, hbf,
          Wq + (size_t)(l + 1) * D * D, Wk + (size_t)(l + 1) * D * D,
          Wv + (size_t)(l + 1) * D * D, W1 + (size_t)(l + 1) * D * DFF,
          W2 + (size_t)(l + 1) * DFF * D, wsc);
    } else {
      ln_add_kernel<4><<<2048, 256, 0, stream>>>(
          part, hi_res, ln2s + l * D, ln2b + l * D, h_res, hbf);
    }
  }

  // logits = h @ Wout + bout : BM=256 gemm5, grid 8x250=2000
  wconv_kernel<<<dim3(1000, 32), 256, 0, stream>>>(Wout, wsc, D, V);
  gemm5_kernel<256, 0><<<2000, 512, 0, stream>>>(
      hbf, wsc, bout, nullptr, nullptr, (float*)d_out, nullptr, nullptr,
      2048, V, D, D, 8);
}

// Round 15
// 1081.245 us; speedup vs baseline: 1.0140x; 1.0140x over previous
//
#include <hip/hip_runtime.h>
#include <cstdint>
#include <cstddef>

typedef short bf16x8 __attribute__((ext_vector_type(8)));
typedef float f32x4 __attribute__((ext_vector_type(4)));
typedef unsigned short us4 __attribute__((ext_vector_type(4)));

#define DEV static __device__ __forceinline__

DEV unsigned short f2bf(float f) {
  union { float f; unsigned u; } v; v.f = f;
  unsigned r = v.u + 0x7FFFu + ((v.u >> 16) & 1u);
  return (unsigned short)(r >> 16);
}

DEV void gll16(const void* g, void* l) {
  __builtin_amdgcn_global_load_lds((const __attribute__((address_space(1))) void*)g,
                                   (__attribute__((address_space(3))) void*)l,
                                   16, 0, 0);
}

// ---------------------------------------------------------------------------
// Device bodies (shared by fused wrappers)
// ---------------------------------------------------------------------------
DEV void embed_body(const int* __restrict__ x, const float* __restrict__ te,
                    const float* __restrict__ pe, float* __restrict__ hf,
                    unsigned short* __restrict__ hb, int row, int tid) {
  int t = row & 1023;
  int tok = x[row];
  float4 v = ((const float4*)(te + (size_t)tok * 1024))[tid];
  float4 p = ((const float4*)(pe + (size_t)t * 1024))[tid];
  v.x += p.x; v.y += p.y; v.z += p.z; v.w += p.w;
  ((float4*)(hf + (size_t)row * 1024))[tid] = v;
  us4 bv; bv[0] = f2bf(v.x); bv[1] = f2bf(v.y); bv[2] = f2bf(v.z); bv[3] = f2bf(v.w);
  ((us4*)(hb + (size_t)row * 1024))[tid] = bv;
}

DEV void wconv_body(const float* __restrict__ W, unsigned short* __restrict__ Wt,
                    int K, int N, int b, float (*tile)[33], int tid) {
  const int nb = N >> 5;
  const int n0 = (b % nb) * 32, k0 = (b / nb) * 32;
  const int tx = tid & 31, ty = tid >> 5;
#pragma unroll
  for (int i = 0; i < 4; ++i)
    tile[ty * 4 + i][tx] = W[(size_t)(k0 + ty * 4 + i) * N + n0 + tx];
  __syncthreads();
#pragma unroll
  for (int i = 0; i < 4; ++i)
    Wt[(size_t)(n0 + ty * 4 + i) * K + k0 + tx] = f2bf(tile[tx][ty * 4 + i]);
}

template <int NP>
DEV void ln_body(const float* __restrict__ a1, const float* __restrict__ res,
                 const float* __restrict__ s, const float* __restrict__ bb,
                 float* __restrict__ out_f, unsigned short* __restrict__ out_b,
                 int row, int tid, float* red) {
  float4 x = ((const float4*)(a1 + (size_t)row * 1024))[tid];
  float4 rv = ((const float4*)(res + (size_t)row * 1024))[tid];
  x.x += rv.x; x.y += rv.y; x.z += rv.z; x.w += rv.w;
#pragma unroll
  for (int pimg = 1; pimg < NP; ++pimg) {
    float4 x2 = ((const float4*)(a1 + (size_t)pimg * 2097152 + (size_t)row * 1024))[tid];
    x.x += x2.x; x.y += x2.y; x.z += x2.z; x.w += x2.w;
  }
  float sum = x.x + x.y + x.z + x.w;
  float sq = x.x * x.x + x.y * x.y + x.z * x.z + x.w * x.w;
#pragma unroll
  for (int mm = 1; mm < 64; mm <<= 1) {
    sum += __shfl_xor(sum, mm, 64);
    sq += __shfl_xor(sq, mm, 64);
  }
  int wid = tid >> 6, lane = tid & 63;
  if (lane == 0) { red[wid] = sum; red[4 + wid] = sq; }
  __syncthreads();
  sum = red[0] + red[1] + red[2] + red[3];
  sq = red[4] + red[5] + red[6] + red[7];
  float mean = sum * (1.f / 1024.f);
  float var = sq * (1.f / 1024.f) - mean * mean;
  float rstd = rsqrtf(var + 1e-5f);
  float4 sv = ((const float4*)s)[tid];
  float4 bv = ((const float4*)bb)[tid];
  float4 y;
  y.x = (x.x - mean) * rstd * sv.x + bv.x;
  y.y = (x.y - mean) * rstd * sv.y + bv.y;
  y.z = (x.z - mean) * rstd * sv.z + bv.z;
  y.w = (x.w - mean) * rstd * sv.w + bv.w;
  ((float4*)(out_f + (size_t)row * 1024))[tid] = y;
  us4 ob; ob[0] = f2bf(y.x); ob[1] = f2bf(y.y); ob[2] = f2bf(y.z); ob[3] = f2bf(y.w);
  ((us4*)(out_b + (size_t)row * 1024))[tid] = ob;
}

DEV void wconv5_select(int bid, const float* Wqf, const float* Wkf,
                       const float* Wvf, const float* W1f, const float* W2f,
                       unsigned short* wsc, float (*tile)[33], int tid) {
  const float* W; unsigned short* Wt; int K, N, b;
  if (bid < 3072) {
    const int sgl = bid >> 10; b = bid & 1023;
    W = sgl == 0 ? Wqf : (sgl == 1 ? Wkf : Wvf);
    Wt = wsc + (size_t)sgl * 1048576; K = 1024; N = 1024;
  } else if (bid < 7168) {
    b = bid - 3072; W = W1f; Wt = wsc + 3145728; K = 1024; N = 4096;
  } else {
    b = bid - 7168; W = W2f; Wt = wsc + 7340032; K = 4096; N = 1024;
  }
  wconv_body(W, Wt, K, N, b, tile, tid);
}

// ---------------------------------------------------------------------------
// Fused wrappers
// ---------------------------------------------------------------------------
__global__ __launch_bounds__(256) void embed_wconv_kernel(
    const int* __restrict__ x, const float* __restrict__ te,
    const float* __restrict__ pe, float* __restrict__ hf,
    unsigned short* __restrict__ hb,
    const float* __restrict__ Wqf, const float* __restrict__ Wkf,
    const float* __restrict__ Wvf, const float* __restrict__ W1f,
    const float* __restrict__ W2f, unsigned short* __restrict__ wsc) {
  __shared__ float tile[32][33];
  const int bid = blockIdx.x;
  if (bid < 2048) {
    embed_body(x, te, pe, hf, hb, bid, threadIdx.x);
    return;
  }
  wconv5_select(bid - 2048, Wqf, Wkf, Wvf, W1f, W2f, wsc, tile, threadIdx.x);
}

template <int NP>
__global__ __launch_bounds__(256) void ln_wconv5_kernel(
    const float* __restrict__ a1, const float* __restrict__ res,
    const float* __restrict__ s, const float* __restrict__ bb,
    float* __restrict__ out_f, unsigned short* __restrict__ out_b,
    const float* __restrict__ Wqf, const float* __restrict__ Wkf,
    const float* __restrict__ Wvf, const float* __restrict__ W1f,
    const float* __restrict__ W2f, unsigned short* __restrict__ wsc) {
  __shared__ float tile[32][33];
  __shared__ float red[8];
  const int bid = blockIdx.x;
  if (bid < 2048) {
    ln_body<NP>(a1, res, s, bb, out_f, out_b, bid, threadIdx.x, red);
    return;
  }
  wconv5_select(bid - 2048, Wqf, Wkf, Wvf, W1f, W2f, wsc, tile, threadIdx.x);
}

template <int NP>
__global__ __launch_bounds__(256) void ln_add_kernel(
    const float* __restrict__ a1, const float* __restrict__ res,
    const float* __restrict__ s, const float* __restrict__ bb,
    float* __restrict__ out_f, unsigned short* __restrict__ out_b) {
  __shared__ float red[8];
  ln_body<NP>(a1, res, s, bb, out_f, out_b, blockIdx.x, threadIdx.x, red);
}

__global__ __launch_bounds__(256) void wconv_kernel(
    const float* __restrict__ W, unsigned short* __restrict__ Wt, int K, int N) {
  __shared__ float tile[32][33];
  const int nb = N >> 5;
  wconv_body(W, Wt, K, N, blockIdx.y * nb + blockIdx.x, tile, threadIdx.x);
}

// ---------------------------------------------------------------------------
// gemm5: 2-phase GEMM (single-buffer, 2 barriers), BM x 128, 8 waves.
// ---------------------------------------------------------------------------
template <int BM, int EPI>
__global__ __launch_bounds__(512) void gemm5_kernel(
    const unsigned short* __restrict__ A, const unsigned short* __restrict__ Bt,
    const float* __restrict__ bias1, const float* __restrict__ bias2,
    const float* __restrict__ bias3, void* __restrict__ C1,
    void* __restrict__ C2, void* __restrict__ C3,
    int M, int N, int Kstride, int klen, int nbm) {
  constexpr int BN = 128, BK = 64;
  constexpr int MFR = BM / 64;
  constexpr int AIT = BM / 64;
  __shared__ unsigned short lA[BM * BK];
  __shared__ unsigned short lB[BN * BK];
  const int tid = threadIdx.x;
  const int wid = tid >> 6, lane = tid & 63;
  const int g = lane >> 4, c = lane & 15;
  const int wm = wid >> 1, wn = wid & 1;

  const int nwg = gridDim.x;
  const int q = nwg >> 3, r = nwg & 7;
  const int xcd = blockIdx.x & 7, jj = blockIdx.x >> 3;
  const int wgid = (xcd < r) ? (xcd * (q + 1) + jj)
                             : (r * (q + 1) + (xcd - r) * q + jj);
  const int bm = (wgid % nbm) * BM;
  const int bn = (wgid / nbm) * BN;
  const int k0 = blockIdx.z * klen;

  f32x4 acc[MFR][4];
#pragma unroll
  for (int mi = 0; mi < MFR; ++mi)
#pragma unroll
    for (int ni = 0; ni < 4; ++ni) acc[mi][ni] = f32x4{0.f, 0.f, 0.f, 0.f};

  for (int kb = 0; kb < klen; kb += BK) {
#pragma unroll
    for (int it = 0; it < AIT; ++it) {
      int chunk = it * 512 + tid;
      int row = chunk >> 3, cr = chunk & 7;
      int sc = cr ^ (row & 7);
      gll16(A + (size_t)(bm + row) * Kstride + k0 + kb + sc * 8,
            lA + (size_t)(it * 512 + wid * 64) * 8);
    }
#pragma unroll
    for (int it = 0; it < 2; ++it) {
      int chunk = it * 512 + tid;
      int row = chunk >> 3, cr = chunk & 7;
      int sc = cr ^ (row & 7);
      gll16(Bt + (size_t)(bn + row) * Kstride + k0 + kb + sc * 8,
            lB + (size_t)(it * 512 + wid * 64) * 8);
    }
    __syncthreads();
#pragma unroll
    for (int kk = 0; kk < 2; ++kk) {
      bf16x8 af[MFR], bfr[4];
#pragma unroll
      for (int mi = 0; mi < MFR; ++mi) {
        int row = wm * (BM / 4) + mi * 16 + c;
        int ch = (kk * 4 + g) ^ (row & 7);
        af[mi] = *(const bf16x8*)(lA + row * BK + ch * 8);
      }
#pragma unroll
      for (int ni = 0; ni < 4; ++ni) {
        int row = wn * 64 + ni * 16 + c;
        int ch = (kk * 4 + g) ^ (row & 7);
        bfr[ni] = *(const bf16x8*)(lB + row * BK + ch * 8);
      }
#pragma unroll
      for (int mi = 0; mi < MFR; ++mi)
#pragma unroll
        for (int ni = 0; ni < 4; ++ni)
          acc[mi][ni] = __builtin_amdgcn_mfma_f32_16x16x32_bf16(
              af[mi], bfr[ni], acc[mi][ni], 0, 0, 0);
    }
    __syncthreads();
  }

  const bool z0 = (blockIdx.z == 0);
#pragma unroll
  for (int mi = 0; mi < MFR; ++mi) {
    const int row0 = bm + wm * (BM / 4) + mi * 16 + g * 4;
#pragma unroll
    for (int ni = 0; ni < 4; ++ni) {
      const int col = bn + wn * 64 + ni * 16 + c;
      if constexpr (EPI == 0) {
        float* C = (float*)C1 + (size_t)blockIdx.z * M * N;
        const float bv = z0 ? bias1[col] : 0.f;
#pragma unroll
        for (int rr = 0; rr < 4; ++rr)
          C[(size_t)(row0 + rr) * N + col] = acc[mi][ni][rr] + bv;
      } else if constexpr (EPI == 2) {
        const float bv = bias1[col];
#pragma unroll
        for (int rr = 0; rr < 4; ++rr)
          ((unsigned short*)C1)[(size_t)(row0 + rr) * N + col] =
              f2bf(fmaxf(acc[mi][ni][rr] + bv, 0.f));
      } else {  // EPI == 4: QKV scatter
        if (col < 1024) {
          const float bv = bias1[col];
#pragma unroll
          for (int rr = 0; rr < 4; ++rr)
            ((unsigned short*)C1)[(size_t)(row0 + rr) * 1024 + col] =
                f2bf(acc[mi][ni][rr] + bv);
        } else if (col < 2048) {
          const float bv = bias2[col - 1024];
#pragma unroll
          for (int rr = 0; rr < 4; ++rr)
            ((unsigned short*)C2)[(size_t)(row0 + rr) * 1024 + (col - 1024)] =
                f2bf(acc[mi][ni][rr] + bv);
        } else {
          const int cp = col - 2048;
          const float bv = bias3[cp];
          const int hh = cp >> 6, hd = cp & 63;
#pragma unroll
          for (int rr = 0; rr < 4; ++rr) {
            const int row = row0 + rr;
            const int b = row >> 10, t = row & 1023;
            ((unsigned short*)C3)[(size_t)((b * 16 + hh) * 64 + hd) * 1024 + t] =
                f2bf(acc[mi][ni][rr] + bv);
          }
        }
      }
    }
  }
}

// ---------------------------------------------------------------------------
// Flash attention, QBLK=64, KVBLK=128 (r12 best config): 256 threads, 4 waves.
// ---------------------------------------------------------------------------
__global__ __launch_bounds__(256) void attn_kernel(
    const unsigned short* __restrict__ q, const unsigned short* __restrict__ k,
    const unsigned short* __restrict__ vt, float* __restrict__ o) {
  __shared__ unsigned short lK[128 * 64];
  __shared__ unsigned short lV[64 * 128];
  __shared__ unsigned short lP[4][16 * 128];
  const int tid = threadIdx.x, wid = tid >> 6, lane = tid & 63;
  const int g = lane >> 4, c = lane & 15;
  const int qb = blockIdx.x * 64;
  const int h = blockIdx.y;
  const int b = blockIdx.z;
  const int qw = qb + wid * 16;

  bf16x8 aq[2];
#pragma unroll
  for (int kk = 0; kk < 2; ++kk)
    aq[kk] = *(const bf16x8*)(q + (size_t)(b * 1024 + qw + c) * 1024 + h * 64 + kk * 32 + g * 8);

  float m_run[4], l_run[4];
  f32x4 acc_o[4];
#pragma unroll
  for (int rr = 0; rr < 4; ++rr) { m_run[rr] = -INFINITY; l_run[rr] = 0.f; }
#pragma unroll
  for (int ni = 0; ni < 4; ++ni) acc_o[ni] = f32x4{0.f, 0.f, 0.f, 0.f};

  const int ntiles = (qb >> 7) + 1;
  for (int kt = 0; kt < ntiles; ++kt) {
#pragma unroll
    for (int it = 0; it < 4; ++it) {
      int chunk = it * 256 + tid;
      int row = chunk >> 3, cr = chunk & 7;
      int sc = cr ^ (row & 7);
      gll16(k + (size_t)(b * 1024 + kt * 128 + row) * 1024 + h * 64 + sc * 8,
            lK + (size_t)(it * 256 + wid * 64) * 8);
    }
#pragma unroll
    for (int it = 0; it < 4; ++it) {
      int chunk = it * 256 + tid;
      int row = chunk >> 4, cr = chunk & 15;
      int sc = cr ^ (row & 7);
      gll16(vt + (size_t)((b * 16 + h) * 64 + row) * 1024 + kt * 128 + sc * 8,
            lV + (size_t)(it * 256 + wid * 64) * 8);
    }
    __syncthreads();

    f32x4 accs[8];
#pragma unroll
    for (int ni = 0; ni < 8; ++ni) accs[ni] = f32x4{0.f, 0.f, 0.f, 0.f};
    __builtin_amdgcn_s_setprio(1);
#pragma unroll
    for (int kk = 0; kk < 2; ++kk)
#pragma unroll
      for (int ni = 0; ni < 8; ++ni) {
        int row = ni * 16 + c;
        int ch = (kk * 4 + g) ^ (row & 7);
        bf16x8 kf = *(const bf16x8*)(lK + row * 64 + ch * 8);
        accs[ni] = __builtin_amdgcn_mfma_f32_16x16x32_bf16(aq[kk], kf, accs[ni], 0, 0, 0);
      }
    __builtin_amdgcn_s_setprio(0);

    const bool diag = (kt == ntiles - 1);
    float p[8][4], rowmax[4];
#pragma unroll
    for (int rr = 0; rr < 4; ++rr) rowmax[rr] = -INFINITY;
#pragma unroll
    for (int ni = 0; ni < 8; ++ni)
#pragma unroll
      for (int rr = 0; rr < 4; ++rr) {
        float s = accs[ni][rr] * 0.125f;
        if (diag) {
          int ktok = kt * 128 + ni * 16 + c;
          int qtok = qw + g * 4 + rr;
          if (ktok > qtok) s = -INFINITY;
        }
        p[ni][rr] = s;
        rowmax[rr] = fmaxf(rowmax[rr], s);
      }
#pragma unroll
    for (int mm = 1; mm < 16; mm <<= 1)
#pragma unroll
      for (int rr = 0; rr < 4; ++rr)
        rowmax[rr] = fmaxf(rowmax[rr], __shfl_xor(rowmax[rr], mm, 64));

    float alpha[4];
#pragma unroll
    for (int rr = 0; rr < 4; ++rr) {
      float mn = fmaxf(m_run[rr], rowmax[rr]);
      alpha[rr] = __expf(m_run[rr] - mn);
      m_run[rr] = mn;
    }
#pragma unroll
    for (int ni = 0; ni < 8; ++ni)
#pragma unroll
      for (int rr = 0; rr < 4; ++rr) p[ni][rr] = __expf(p[ni][rr] - m_run[rr]);

    float rowsum[4];
#pragma unroll
    for (int rr = 0; rr < 4; ++rr)
      rowsum[rr] = ((p[0][rr] + p[1][rr]) + (p[2][rr] + p[3][rr])) +
                   ((p[4][rr] + p[5][rr]) + (p[6][rr] + p[7][rr]));
#pragma unroll
    for (int mm = 1; mm < 16; mm <<= 1)
#pragma unroll
      for (int rr = 0; rr < 4; ++rr) rowsum[rr] += __shfl_xor(rowsum[rr], mm, 64);
#pragma unroll
    for (int rr = 0; rr < 4; ++rr) l_run[rr] = l_run[rr] * alpha[rr] + rowsum[rr];
#pragma unroll
    for (int ni = 0; ni < 4; ++ni)
#pragma unroll
      for (int rr = 0; rr < 4; ++rr) acc_o[ni][rr] *= alpha[rr];

#pragma unroll
    for (int ni = 0; ni < 8; ++ni)
#pragma unroll
      for (int rr = 0; rr < 4; ++rr) {
        int qrow = g * 4 + rr;
        int tok = ni * 16 + c;
        int ch = (tok >> 3) ^ (qrow & 7);
        lP[wid][qrow * 128 + ch * 8 + (tok & 7)] = f2bf(p[ni][rr]);
      }

    __builtin_amdgcn_s_setprio(1);
#pragma unroll
    for (int kk = 0; kk < 4; ++kk) {
      int kc = kk * 4 + g;
      int chp = kc ^ (c & 7);
      bf16x8 pa = *(const bf16x8*)(&lP[wid][c * 128 + chp * 8]);
#pragma unroll
      for (int ni = 0; ni < 4; ++ni) {
        int row = ni * 16 + c;
        int ch = kc ^ (row & 7);
        bf16x8 vf = *(const bf16x8*)(lV + row * 128 + ch * 8);
        acc_o[ni] = __builtin_amdgcn_mfma_f32_16x16x32_bf16(pa, vf, acc_o[ni], 0, 0, 0);
      }
    }
    __builtin_amdgcn_s_setprio(0);
    __syncthreads();
  }

#pragma unroll
  for (int ni = 0; ni < 4; ++ni)
#pragma unroll
    for (int rr = 0; rr < 4; ++rr) {
      int row = b * 1024 + qw + g * 4 + rr;
      int col = h * 64 + ni * 16 + c;
      o[(size_t)row * 1024 + col] = acc_o[ni][rr] / l_run[rr];
    }
}

// ---------------------------------------------------------------------------
extern "C" void kernel_launch(void* const* d_in, const int* in_sizes, int n_in,
                              void* d_out, int out_size, void* d_ws, size_t ws_size,
                              hipStream_t stream) {
  const int D = 1024, DFF = 4096, V = 32000, L = 6;
  const int* x = (const int*)d_in[0];
  const float* tok_emb = (const float*)d_in[1];
  const float* pos_emb = (const float*)d_in[2];
  const float* Wq = (const float*)d_in[3];  const float* bq = (const float*)d_in[4];
  const float* Wk = (const float*)d_in[5];  const float* bk = (const float*)d_in[6];
  const float* Wv = (const float*)d_in[7];  const float* bv = (const float*)d_in[8];
  const float* ln1s = (const float*)d_in[9];  const float* ln1b = (const float*)d_in[10];
  const float* W1 = (const float*)d_in[11];  const float* b1 = (const float*)d_in[12];
  const float* W2 = (const float*)d_in[13];  const float* b2 = (const float*)d_in[14];
  const float* ln2s = (const float*)d_in[15]; const float* ln2b = (const float*)d_in[16];
  const float* Wout = (const float*)d_in[17]; const float* bout = (const float*)d_in[18];

  char* ws = (char*)d_ws;
  float* h_res = (float*)(ws + 0);                     //  8 MB [2048][1024] f32
  float* hi_res = (float*)(ws + 8388608);              //  8 MB
  float* tmp = (float*)(ws + 16777216);                //  8 MB (attn out)
  unsigned short* hbf = (unsigned short*)(ws + 25165824);   // 4 MB
  unsigned short* qb_ = (unsigned short*)(ws + 29360128);   // 4 MB
  unsigned short* kb_ = (unsigned short*)(ws + 33554432);   // 4 MB
  unsigned short* vtb = (unsigned short*)(ws + 37748736);   // 4 MB V^T
  unsigned short* ffn1 = (unsigned short*)(ws + 41943040);  // 16 MB [2048][4096]
  unsigned short* wsc = (unsigned short*)(ws + 58720256);   // weights (64MB for logits)
  float* part = (float*)(ws + 58720256 + 25165824);    // 32 MB FFN2 partials
  // (part aliases the logits-weight zone; wconv_out runs after last part use)

  // embed + wconv5(layer 0) fused
  embed_wconv_kernel<<<13312, 256, 0, stream>>>(
      x, tok_emb, pos_emb, h_res, hbf,
      Wq, Wk, Wv, W1, W2, wsc);

  for (int l = 0; l < L; ++l) {
    // QKV fused GEMM (N=3072): BM=128, grid 16x24=384 blocks
    gemm5_kernel<128, 4><<<384, 512, 0, stream>>>(
        hbf, wsc, bq + l * D, bk + l * D, bv + l * D, qb_, kb_, vtb,
        2048, 3072, D, D, 16);
    // attention (QBLK=64, KVBLK=128) -> tmp
    attn_kernel<<<dim3(16, 16, 2), 256, 0, stream>>>(qb_, kb_, vtb, tmp);
    // hi = LN1(attn + h)
    ln_add_kernel<1><<<2048, 256, 0, stream>>>(
        tmp, h_res, ln1s + l * D, ln1b + l * D, hi_res, hbf);
    // FFN1 (relu, bf16 out): grid 8x32=256
    gemm5_kernel<256, 2><<<256, 512, 0, stream>>>(
        hbf, wsc + 3145728, b1 + l * DFF, nullptr, nullptr, ffn1, nullptr, nullptr,
        2048, DFF, D, D, 8);
    // FFN2 split-K=4 -> part[0..3]
    gemm5_kernel<256, 0><<<dim3(64, 1, 4), 512, 0, stream>>>(
        ffn1, wsc + 7340032, b2 + l * D, nullptr, nullptr, part, nullptr, nullptr,
        2048, D, DFF, 1024, 8);
    // h = LN2(part0..3 + hi), fused with wconv5 of NEXT layer
    if (l < L - 1) {
      ln_wconv5_kernel<4><<<13312, 256, 0, stream>>>(
          part, hi_res, ln2s + l * D, ln2b + l * D, h_res, hbf,
          Wq + (size_t)(l + 1) * D * D, Wk + (size_t)(l + 1) * D * D,
          Wv + (size_t)(l + 1) * D * D, W1 + (size_t)(l + 1) * D * DFF,
          W2 + (size_t)(l + 1) * DFF * D, wsc);
    } else {
      ln_add_kernel<4><<<2048, 256, 0, stream>>>(
          part, hi_res, ln2s + l * D, ln2b + l * D, h_res, hbf);
    }
  }

  // logits = h @ Wout + bout : BM=256 gemm5, grid 8x250=2000
  wconv_kernel<<<dim3(1000, 32), 256, 0, stream>>>(Wout, wsc, D, V);
  gemm5_kernel<256, 0><<<2000, 512, 0, stream>>>(
      hbf, wsc, bout, nullptr, nullptr, (float*)d_out, nullptr, nullptr,
      2048, V, D, D, 8);
}